// Round 4
// baseline (132.340 us; speedup 1.0000x reference)
//
#include <hip/hip_runtime.h>

#define NUMC 14
#define FD 128
#define SPATIAL (16*128*128)      // 262144 per batch = 2^18
#define N_TOTAL (2*SPATIAL)       // 524288
#define NV 50
#define NH 25
#define TC 13
#define QLEN 4096
#define MCH 64                    // negatives per k_neg block
#define NCHUNK 32                 // 2048 / MCH
#define CHUNK 1024
#define NBLKP (N_TOTAL / CHUNK)   // 512 (k_prep blocks)
#define THRESH_F 0.3f

// k_sums geometry
#define CGRP 8                    // channels per thread
#define NCG (FD / CGRP)           // 16 channel groups
#define PPT 64                    // pixel-iters per thread
#define PXBLK (256 * PPT)         // 16384 pixels per block
#define NPB (N_TOTAL / PXBLK)     // 32 pixel blocks
#define NSUMBLK (NCG * NPB)       // 512 blocks
#define PARTW (NUMC * CGRP)       // 112 floats per wave partial

// ws offsets in 4-byte units
#define WS_SEL     0              // int[656]
#define WS_ANORM   656            // float[656]
#define WS_CNTS    1312           // float[16]
#define WS_SUMS    1328           // float[14*128]
#define WS_NEGPART 3120           // float[650*32]
#define WS_AROWS   23920          // float[650*128]
#define WS_LOSSP   107120         // float[13]
#define WS_PART    107200         // float[512*4*112] = 229376
#define WS_CNTPART 336576         // int[512*16]
#define WS_LAB8    344768         // uchar[524288]

__global__ void k_select(const int* __restrict__ labels, const int* __restrict__ predict,
                         const float* __restrict__ prob, int* __restrict__ sel) {
    int cat = blockIdx.x;              // 0..25
    int c = 1 + (cat >> 1);
    bool hard = (cat & 1) == 0;
    int lane = threadIdx.x;            // 0..63
    int* slot = sel + (c - 1) * NV + (hard ? 0 : NH);
    int found = 0;
    for (int base = 0; base < N_TOTAL && found < NH; base += 64) {
        int n = base + lane;
        bool m = false;
        if (n < N_TOTAL) {
            int pr = predict[n];
            if (pr == c && prob[n] > THRESH_F) {
                int lb = labels[n];
                m = hard ? (lb != c) : (lb == c);
            }
        }
        unsigned long long mask = __ballot(m);
        int rank = __popcll(mask & ((1ull << lane) - 1ull));
        if (m && (found + rank) < NH) slot[found + rank] = n;
        found += __popcll(mask);
    }
    if (lane >= found && lane < NH) slot[lane] = N_TOTAL - 1;
}

// labels+prob -> 1-byte class id (0..13 valid, 15 invalid) + per-block class counts
__global__ __launch_bounds__(256) void k_prep(const int* __restrict__ labels,
        const float* __restrict__ prob, unsigned char* __restrict__ lab8,
        int* __restrict__ cntpart) {
    __shared__ int cnt_s[16];
    int tid = threadIdx.x;
    int lane = tid & 63;
    int base = blockIdx.x * CHUNK;
    if (tid < 16) cnt_s[tid] = 0;
    __syncthreads();
    int n = base + tid * 4;
    int4   lb = *(const int4*)(labels + n);
    float4 pv = *(const float4*)(prob + n);
    int l0 = pv.x > THRESH_F ? (lb.x & 15) : 15;
    int l1 = pv.y > THRESH_F ? (lb.y & 15) : 15;
    int l2 = pv.z > THRESH_F ? (lb.z & 15) : 15;
    int l3 = pv.w > THRESH_F ? (lb.w & 15) : 15;
    uchar4 o;
    o.x = (unsigned char)l0; o.y = (unsigned char)l1;
    o.z = (unsigned char)l2; o.w = (unsigned char)l3;
    *(uchar4*)(lab8 + n) = o;
    #pragma unroll
    for (int c = 0; c < 16; ++c) {
        if (c == 14) continue;
        int cnt = __popcll(__ballot(l0 == c)) + __popcll(__ballot(l1 == c))
                + __popcll(__ballot(l2 == c)) + __popcll(__ballot(l3 == c));
        if (lane == 0 && cnt) atomicAdd(&cnt_s[c], cnt);
    }
    __syncthreads();
    if (tid < 16) cntpart[blockIdx.x * 16 + tid] = cnt_s[tid];
}

// per-class sums: register accumulators [14][8], branchless masks, no LDS in loop
__global__ __launch_bounds__(256) void k_sums(const float* __restrict__ feats,
        const unsigned char* __restrict__ lab8, float* __restrict__ part) {
    int tid = threadIdx.x;
    int g  = blockIdx.x >> 5;          // channel group 0..15
    int pb = blockIdx.x & 31;          // pixel block 0..31
    int px0 = pb * PXBLK;
    int b   = px0 >> 18;
    int sp0 = px0 & (SPATIAL - 1);
    const float* fp = feats + (size_t)(b * FD + g * CGRP) * SPATIAL + sp0;
    const unsigned char* lp = lab8 + (size_t)b * SPATIAL + sp0;

    float acc[NUMC][CGRP];
    #pragma unroll
    for (int c = 0; c < NUMC; ++c)
        #pragma unroll
        for (int j = 0; j < CGRP; ++j) acc[c][j] = 0.f;

    #pragma unroll 2
    for (int i = 0; i < PPT; ++i) {
        int off = (i << 8) + tid;
        int l = lp[off];
        float v[CGRP];
        #pragma unroll
        for (int j = 0; j < CGRP; ++j)
            v[j] = __builtin_nontemporal_load(fp + (size_t)j * SPATIAL + off);
        float m[NUMC];
        #pragma unroll
        for (int c = 0; c < NUMC; ++c) m[c] = (l == c) ? 1.f : 0.f;
        #pragma unroll
        for (int c = 0; c < NUMC; ++c)
            #pragma unroll
            for (int j = 0; j < CGRP; ++j)
                acc[c][j] = fmaf(m[c], v[j], acc[c][j]);
    }

    // wave-level reduce, per-wave partial out
    int lane = tid & 63, w = tid >> 6;
    float* pw = part + ((size_t)blockIdx.x * 4 + w) * PARTW;
    #pragma unroll
    for (int c = 0; c < NUMC; ++c)
        #pragma unroll
        for (int j = 0; j < CGRP; ++j) {
            float x = acc[c][j];
            #pragma unroll
            for (int o = 32; o; o >>= 1) x += __shfl_xor(x, o);
            if (lane == 0) pw[c * CGRP + j] = x;
        }
}

__global__ __launch_bounds__(256) void k_reduce(const float* __restrict__ part,
        const int* __restrict__ cntpart, float* __restrict__ sums, float* __restrict__ cnts) {
    int idx = blockIdx.x * 256 + threadIdx.x;
    if (idx < NUMC * FD) {
        int cls = idx >> 7, ch = idx & 127;
        int g = ch >> 3, cj = ch & 7;
        const float* pp = part + (size_t)g * (32 * 4 * PARTW) + cls * CGRP + cj;
        float s = 0.f;
        for (int t = 0; t < 128; ++t) s += pp[(size_t)t * PARTW];
        sums[idx] = s;   // layout [class][128]
    } else if (idx < NUMC * FD + 16) {
        int j = idx - NUMC * FD;
        int s = 0;
        for (int b = 0; b < NBLKP; ++b) s += cntpart[b * 16 + j];
        cnts[j] = (float)s;
    }
}

__global__ __launch_bounds__(128) void k_gather(const float* __restrict__ feats,
        const int* __restrict__ sel, float* __restrict__ arows, float* __restrict__ anorm) {
    __shared__ float red[2];
    int r = blockIdx.x;          // 0..649
    int t = threadIdx.x;         // 0..127 = channel
    int n = sel[r];
    int b = n >> 18, sp = n & (SPATIAL - 1);
    float v = feats[((size_t)(b * FD + t)) * SPATIAL + sp];
    arows[r * FD + t] = v;
    float a = v * v;
    #pragma unroll
    for (int o = 32; o; o >>= 1) a += __shfl_xor(a, o);
    if ((t & 63) == 0) red[t >> 6] = a;
    __syncthreads();
    if (t == 0) anorm[r] = sqrtf(red[0] + red[1]);
}

__global__ __launch_bounds__(256) void k_neg(const float* __restrict__ queue,
        const float* __restrict__ arows, const float* __restrict__ anorm,
        float* __restrict__ negpart) {
    constexpr int NSTR = FD + 4;
    __shared__ float a_s[NV * FD];
    __shared__ float n_s[MCH * NSTR];
    __shared__ float an_s[NV];
    int tid = threadIdx.x;
    int ci = blockIdx.x >> 5;      // 0..12
    int chunk = blockIdx.x & 31;   // 0..31
    const float* ap = arows + ci * (NV * FD);
    for (int i = tid; i < NV * FD / 4; i += 256) ((float4*)a_s)[i] = ((const float4*)ap)[i];
    if (tid < NV) an_s[tid] = anorm[ci * NV + tid];
    const float* qp = queue + ((size_t)(ci + 1) * QLEN + (QLEN / 2) + chunk * MCH) * (size_t)FD;
    for (int i = tid; i < MCH * FD / 4; i += 256) {
        int m = i / (FD / 4), k4 = i % (FD / 4);
        ((float4*)(n_s + m * NSTR))[k4] = ((const float4*)qp)[i];
    }
    __syncthreads();
    int lane = tid & 63, w = tid >> 6;
    float4 nr[FD / 4];
    const float4* nrow = (const float4*)(n_s + lane * NSTR);
    float sq = 0.f;
    #pragma unroll
    for (int k = 0; k < FD / 4; ++k) {
        nr[k] = nrow[k];
        sq += nr[k].x*nr[k].x + nr[k].y*nr[k].y + nr[k].z*nr[k].z + nr[k].w*nr[k].w;
    }
    float inn = 10.f / sqrtf(sq);   // 1/TEMP folded in
    float* np = negpart + (ci * NV) * NCHUNK + chunk;   // transposed: [row][chunk]
    for (int v = w; v < NV; v += 4) {
        const float4* a4 = (const float4*)(a_s + v * FD);
        float dot = 0.f;
        #pragma unroll
        for (int k = 0; k < FD / 4; ++k) {
            float4 x = a4[k];
            dot += x.x*nr[k].x + x.y*nr[k].y + x.z*nr[k].z + x.w*nr[k].w;
        }
        float e = __expf(dot * inn / an_s[v]);
        #pragma unroll
        for (int o = 32; o; o >>= 1) e += __shfl_xor(e, o);
        if (lane == 0) np[v * NCHUNK] = e;
    }
}

// per-class loss partials: 13 blocks
__global__ __launch_bounds__(256) void k_final_a(const float* __restrict__ arows,
        const float* __restrict__ anorm, const float* __restrict__ sums,
        const float* __restrict__ cnts, const float* __restrict__ negpart,
        float* __restrict__ lossp) {
    __shared__ float p_s[FD];
    __shared__ float red_s[2];
    __shared__ float lacc[8];
    int tid = threadIdx.x;
    int ci = blockIdx.x, c = ci + 1;
    if (tid < 128) p_s[tid] = sums[c * FD + tid] / cnts[c];
    __syncthreads();
    if (tid < 128) {
        float q = p_s[tid] * p_s[tid];
        #pragma unroll
        for (int o = 32; o; o >>= 1) q += __shfl_xor(q, o);
        if ((tid & 63) == 0) red_s[tid >> 6] = q;
    }
    __syncthreads();
    float inv10 = 10.f / sqrtf(red_s[0] + red_s[1]);   // 1/(pn*TEMP)
    int grp = tid >> 5, l32 = tid & 31;
    float acc = 0.f;
    for (int r = grp; r < NV; r += 8) {
        int ar = ci * NV + r;
        float4 x = ((const float4*)arows)[ar * 32 + l32];
        float4 y = ((const float4*)p_s)[l32];
        float d = x.x*y.x + x.y*y.y + x.z*y.z + x.w*y.w;
        float ns = negpart[ar * 32 + l32];
        #pragma unroll
        for (int o = 16; o; o >>= 1) { d += __shfl_xor(d, o); ns += __shfl_xor(ns, o); }
        if (l32 == 0) {
            float logit = d * inv10 / anorm[ar];
            acc += -logit + logf(__expf(logit) + ns);
        }
    }
    if (l32 == 0) lacc[grp] = acc;
    __syncthreads();
    if (tid == 0) {
        float s = 0.f;
        #pragma unroll
        for (int i = 0; i < 8; ++i) s += lacc[i];
        lossp[ci] = s;
    }
}

__global__ void k_final_b(const float* __restrict__ lossp, float* __restrict__ out) {
    int tid = threadIdx.x;   // 64 threads
    float v = (tid < TC) ? lossp[tid] : 0.f;
    #pragma unroll
    for (int o = 32; o; o >>= 1) v += __shfl_xor(v, o);
    if (tid == 0) out[0] = v * (1.f / (TC * NV));
}

extern "C" void kernel_launch(void* const* d_in, const int* in_sizes, int n_in,
                              void* d_out, int out_size, void* d_ws, size_t ws_size,
                              hipStream_t stream) {
    (void)in_sizes; (void)n_in; (void)out_size; (void)ws_size;
    const float* feats   = (const float*)d_in[0];
    const int*   labels  = (const int*)d_in[1];
    const int*   predict = (const int*)d_in[2];
    const float* prob    = (const float*)d_in[3];
    const float* queue   = (const float*)d_in[4];
    float* ws  = (float*)d_ws;
    float* out = (float*)d_out;

    int*   sel     = (int*)(ws + WS_SEL);
    float* anorm   = ws + WS_ANORM;
    float* cnts    = ws + WS_CNTS;
    float* sums    = ws + WS_SUMS;
    float* negpart = ws + WS_NEGPART;
    float* arows   = ws + WS_AROWS;
    float* lossp   = ws + WS_LOSSP;
    float* part    = ws + WS_PART;
    int*   cntpart = (int*)(ws + WS_CNTPART);
    unsigned char* lab8 = (unsigned char*)(ws + WS_LAB8);

    k_select <<<26, 64, 0, stream>>>(labels, predict, prob, sel);
    k_prep   <<<NBLKP, 256, 0, stream>>>(labels, prob, lab8, cntpart);
    k_sums   <<<NSUMBLK, 256, 0, stream>>>(feats, lab8, part);
    k_reduce <<<8, 256, 0, stream>>>(part, cntpart, sums, cnts);
    k_gather <<<TC * NV, 128, 0, stream>>>(feats, sel, arows, anorm);
    k_neg    <<<TC * NCHUNK, 256, 0, stream>>>(queue, arows, anorm, negpart);
    k_final_a<<<TC, 256, 0, stream>>>(arows, anorm, sums, cnts, negpart, lossp);
    k_final_b<<<1, 64, 0, stream>>>(lossp, out);
}

// Round 5
// 117.481 us; speedup vs baseline: 1.1265x; 1.1265x over previous
//
#include <hip/hip_runtime.h>

#define NUMC 14
#define FD 128
#define SPATIAL (16*128*128)      // 262144 per batch = 2^18
#define N_TOTAL (2*SPATIAL)       // 524288
#define NV 50
#define NH 25
#define TC 13
#define QLEN 4096
#define MCH 64                    // negatives per neg-block
#define NCHUNK 32                 // 2048 / MCH
#define NSTR (FD + 4)             // 132: queue row stride in LDS
#define NSUMBLK 2048              // 256 planes x 8 chunks
#define NNEGBLK (TC * NCHUNK)     // 416
#define PXB 32768                 // pixels per sums block
#define THRESH_F 0.3f
#define RSTR 65                   // per-thread LDS stride: 4 regions x 16 + 1 pad

// ws offsets in 4-byte units
#define WS_SEL     0              // int[656]
#define WS_LOSSP   656            // float[13]
#define WS_CNT0    672            // int[1]
#define WS_NEGPART 680            // float[650*32] = 20800
#define WS_PART    21480          // float[2048*4*16] = 131072
#define WS_LAB8    152552         // uchar[524288] = 131072 words

// ---------------- kernel 1: label prep + anchor select + init ----------------
__global__ __launch_bounds__(256) void k_pre(const int* __restrict__ labels,
        const int* __restrict__ predict, const float* __restrict__ prob,
        unsigned char* __restrict__ lab8, int* __restrict__ sel, int* __restrict__ cnt0) {
    int blk = blockIdx.x;
    int tid = threadIdx.x;
    if (blk < 512) {
        int n = blk * 1024 + tid * 4;
        int4   lb = *(const int4*)(labels + n);
        float4 pv = *(const float4*)(prob + n);
        uchar4 o;
        o.x = pv.x > THRESH_F ? (unsigned char)(lb.x & 15) : (unsigned char)15;
        o.y = pv.y > THRESH_F ? (unsigned char)(lb.y & 15) : (unsigned char)15;
        o.z = pv.z > THRESH_F ? (unsigned char)(lb.z & 15) : (unsigned char)15;
        o.w = pv.w > THRESH_F ? (unsigned char)(lb.w & 15) : (unsigned char)15;
        *(uchar4*)(lab8 + n) = o;
    } else if (blk < 538) {
        if (tid >= 64) return;
        int cat = blk - 512;               // 0..25
        int c = 1 + (cat >> 1);
        bool hard = (cat & 1) == 0;
        int lane = tid;
        int* slot = sel + (c - 1) * NV + (hard ? 0 : NH);
        int found = 0;
        for (int base = 0; base < N_TOTAL && found < NH; base += 64) {
            int n = base + lane;
            bool m = false;
            int pr = predict[n];
            if (pr == c && prob[n] > THRESH_F) {
                int lb = labels[n];
                m = hard ? (lb != c) : (lb == c);
            }
            unsigned long long mask = __ballot(m);
            int rank = __popcll(mask & ((1ull << lane) - 1ull));
            if (m && (found + rank) < NH) slot[found + rank] = n;
            found += __popcll(mask);
        }
        if (lane >= found && lane < NH) slot[lane] = N_TOTAL - 1;  // OOB-gather clamp
    } else {
        if (tid == 0) cnt0[0] = 0;
    }
}

// ---------------- kernel 2: class sums (blocks < 2048) + negatives (rest) ----------------
#define ACCUM(v, u) do { \
    int i0 = r0 + ((u).x & 15); \
    int i1 = r0 + 16 + ((u).y & 15); \
    int i2 = r0 + 32 + ((u).z & 15); \
    int i3 = r0 + 48 + ((u).w & 15); \
    float a0 = smem[i0], a1 = smem[i1], a2 = smem[i2], a3 = smem[i3]; \
    smem[i0] = a0 + (v).x; smem[i1] = a1 + (v).y; \
    smem[i2] = a2 + (v).z; smem[i3] = a3 + (v).w; \
} while (0)

__global__ __launch_bounds__(256) void k_main(const float* __restrict__ feats,
        const unsigned char* __restrict__ lab8, const float* __restrict__ queue,
        const int* __restrict__ sel, float* __restrict__ part, float* __restrict__ negpart) {
    __shared__ float smem[256 * RSTR];   // 65 KB
    int tid = threadIdx.x;
    int lane = tid & 63, w = tid >> 6;

    if (blockIdx.x < NSUMBLK) {
        // ---- per-class feature sums: 4 disjoint private LDS regions, no barriers ----
        int plane = blockIdx.x >> 3;        // 0..255 = b*128 + ch
        int chunk = blockIdx.x & 7;
        int b = plane >> 7;
        int r0 = tid * RSTR;
        #pragma unroll
        for (int k = 0; k < RSTR; ++k) smem[r0 + k] = 0.f;   // own region only

        const float4* fp4 = (const float4*)(feats + (size_t)plane * SPATIAL) + (chunk << 13);
        const uchar4* lp4 = (const uchar4*)(lab8 + (size_t)b * SPATIAL) + (chunk << 13);
        float4 v0 = fp4[tid],       v1 = fp4[tid + 256];
        uchar4 u0 = lp4[tid],       u1 = lp4[tid + 256];
        for (int i = 0; i < 30; i += 2) {
            float4 p0 = fp4[(i + 2) * 256 + tid];
            uchar4 q0 = lp4[(i + 2) * 256 + tid];
            float4 p1 = fp4[(i + 3) * 256 + tid];
            uchar4 q1 = lp4[(i + 3) * 256 + tid];
            ACCUM(v0, u0);
            ACCUM(v1, u1);
            v0 = p0; u0 = q0; v1 = p1; u1 = q1;
        }
        ACCUM(v0, u0);
        ACCUM(v1, u1);

        // fold 4 regions + wave shuffle-reduce -> per-wave partial
        float* pw = part + (size_t)((blockIdx.x << 2) + w) * 16;
        #pragma unroll
        for (int cc = 0; cc < NUMC; ++cc) {
            float t = smem[r0 + cc] + smem[r0 + 16 + cc]
                    + smem[r0 + 32 + cc] + smem[r0 + 48 + cc];
            #pragma unroll
            for (int o = 32; o; o >>= 1) t += __shfl_xor(t, o);
            if (lane == 0) pw[cc] = t;
        }
    } else {
        // ---- negatives: exp(dot) partial sums; anchors self-gathered via sel ----
        int nb = blockIdx.x - NSUMBLK;
        int ci = nb >> 5;                  // 0..12
        int chunk = nb & 31;               // 0..31
        float* a_s  = smem;                // 6400 floats
        float* n_s  = smem + 6400;         // 64*132 = 8448
        float* an_s = smem + 14848;        // 50
        int*   sel_s = (int*)(smem + 14912);
        if (tid < NV) sel_s[tid] = sel[ci * NV + tid];
        const float* qp = queue + ((size_t)(ci + 1) * QLEN + (QLEN / 2) + chunk * MCH) * (size_t)FD;
        for (int i = tid; i < MCH * FD / 4; i += 256) {
            int m = i / (FD / 4), k4 = i % (FD / 4);
            ((float4*)(n_s + m * NSTR))[k4] = ((const float4*)qp)[i];
        }
        __syncthreads();
        for (int i = tid; i < NV * FD; i += 256) {
            int r = i >> 7, ch = i & 127;
            int n = sel_s[r];
            int b = n >> 18, sp = n & (SPATIAL - 1);
            a_s[i] = feats[(size_t)(b * FD + ch) * SPATIAL + sp];
        }
        __syncthreads();
        for (int r = w; r < NV; r += 4) {
            float x0 = a_s[r * FD + lane], x1 = a_s[r * FD + 64 + lane];
            float q = x0 * x0 + x1 * x1;
            #pragma unroll
            for (int o = 32; o; o >>= 1) q += __shfl_xor(q, o);
            if (lane == 0) an_s[r] = sqrtf(q);
        }
        __syncthreads();
        float4 nr[FD / 4];
        const float4* nrow = (const float4*)(n_s + lane * NSTR);
        float sq = 0.f;
        #pragma unroll
        for (int k = 0; k < FD / 4; ++k) {
            nr[k] = nrow[k];
            sq += nr[k].x*nr[k].x + nr[k].y*nr[k].y + nr[k].z*nr[k].z + nr[k].w*nr[k].w;
        }
        float inn = 10.f / sqrtf(sq);   // 1/TEMP folded in
        float* np = negpart + ((size_t)ci * NV) * NCHUNK + chunk;   // [row][chunk]
        for (int v = w; v < NV; v += 4) {
            const float4* a4 = (const float4*)(a_s + v * FD);  // wave-uniform broadcast
            float dot = 0.f;
            #pragma unroll
            for (int k = 0; k < FD / 4; ++k) {
                float4 x = a4[k];
                dot += x.x*nr[k].x + x.y*nr[k].y + x.z*nr[k].z + x.w*nr[k].w;
            }
            float e = __expf(dot * inn / an_s[v]);
            #pragma unroll
            for (int o = 32; o; o >>= 1) e += __shfl_xor(e, o);
            if (lane == 0) np[(size_t)v * NCHUNK] = e;
        }
    }
}

// ---------------- kernel 3: per-class loss + deterministic final reduce ----------------
__global__ __launch_bounds__(256) void k_loss(const float* __restrict__ feats,
        const int* __restrict__ sel, const float* __restrict__ part,
        const float* __restrict__ negpart, float* __restrict__ lossp,
        int* __restrict__ cnt0, float* __restrict__ out) {
    __shared__ float p_s[FD];
    __shared__ float a_s[NV * FD];
    __shared__ float an_s[NV];
    __shared__ int   sel_s[NV];
    __shared__ float red_s[2];
    __shared__ float lacc[8];
    int tid = threadIdx.x;
    int ci = blockIdx.x, c = ci + 1;
    if (tid < NV) sel_s[tid] = sel[ci * NV + tid];
    // class sum reduce (cnt cancels under l2-normalization -> use raw sums)
    if (tid < 128) {
        const float* pp = part + c;
        float s = 0.f;
        #pragma unroll
        for (int p = 0; p < 2; ++p) {
            int pl = tid + (p << 7);
            for (int k = 0; k < 32; ++k) s += pp[(size_t)(pl * 32 + k) * 16];
        }
        p_s[tid] = s;
    }
    __syncthreads();
    if (tid < 128) {
        float q = p_s[tid] * p_s[tid];
        #pragma unroll
        for (int o = 32; o; o >>= 1) q += __shfl_xor(q, o);
        if ((tid & 63) == 0) red_s[tid >> 6] = q;
    }
    // gather anchors (L2-warm from k_main)
    for (int i = tid; i < NV * FD; i += 256) {
        int r = i >> 7, ch = i & 127;
        int n = sel_s[r];
        int b = n >> 18, sp = n & (SPATIAL - 1);
        a_s[i] = feats[(size_t)(b * FD + ch) * SPATIAL + sp];
    }
    __syncthreads();
    float pninv10 = 10.f * rsqrtf(red_s[0] + red_s[1]);   // 1/(||sum|| * TEMP)
    int lane = tid & 63, w = tid >> 6;
    for (int r = w; r < NV; r += 4) {
        float x0 = a_s[r * FD + lane], x1 = a_s[r * FD + 64 + lane];
        float q = x0 * x0 + x1 * x1;
        #pragma unroll
        for (int o = 32; o; o >>= 1) q += __shfl_xor(q, o);
        if (lane == 0) an_s[r] = sqrtf(q);
    }
    __syncthreads();
    int grp = tid >> 5, l32 = tid & 31;
    float acc = 0.f;
    for (int r = grp; r < NV; r += 8) {
        const float4* a4 = (const float4*)(a_s + r * FD);
        const float4* p4 = (const float4*)p_s;
        float4 x = a4[l32], y = p4[l32];
        float d = x.x*y.x + x.y*y.y + x.z*y.z + x.w*y.w;
        float ns = negpart[(size_t)(ci * NV + r) * 32 + l32];
        #pragma unroll
        for (int o = 16; o; o >>= 1) { d += __shfl_xor(d, o); ns += __shfl_xor(ns, o); }
        if (l32 == 0) {
            float logit = d * pninv10 / an_s[r];
            acc += -logit + logf(__expf(logit) + ns);
        }
    }
    if (l32 == 0) lacc[grp] = acc;
    __syncthreads();
    if (tid == 0) {
        float s = 0.f;
        #pragma unroll
        for (int i = 0; i < 8; ++i) s += lacc[i];
        lossp[ci] = s;
        __threadfence();
        int t = atomicAdd(cnt0, 1);
        if (t == TC - 1) {                  // last block: deterministic-order final sum
            __threadfence();
            float tot = 0.f;
            for (int i = 0; i < TC; ++i)
                tot += __hip_atomic_load(lossp + i, __ATOMIC_RELAXED, __HIP_MEMORY_SCOPE_AGENT);
            out[0] = tot * (1.f / (TC * NV));
        }
    }
}

extern "C" void kernel_launch(void* const* d_in, const int* in_sizes, int n_in,
                              void* d_out, int out_size, void* d_ws, size_t ws_size,
                              hipStream_t stream) {
    (void)in_sizes; (void)n_in; (void)out_size; (void)ws_size;
    const float* feats   = (const float*)d_in[0];
    const int*   labels  = (const int*)d_in[1];
    const int*   predict = (const int*)d_in[2];
    const float* prob    = (const float*)d_in[3];
    const float* queue   = (const float*)d_in[4];
    float* ws  = (float*)d_ws;
    float* out = (float*)d_out;

    int*   sel     = (int*)(ws + WS_SEL);
    float* lossp   = ws + WS_LOSSP;
    int*   cnt0    = (int*)(ws + WS_CNT0);
    float* negpart = ws + WS_NEGPART;
    float* part    = ws + WS_PART;
    unsigned char* lab8 = (unsigned char*)(ws + WS_LAB8);

    k_pre  <<<539, 256, 0, stream>>>(labels, predict, prob, lab8, sel, cnt0);
    k_main <<<NSUMBLK + NNEGBLK, 256, 0, stream>>>(feats, lab8, queue, sel, part, negpart);
    k_loss <<<TC, 256, 0, stream>>>(feats, sel, part, negpart, lossp, cnt0, out);
}